// Round 8
// baseline (389.843 us; speedup 1.0000x reference)
//
#include <hip/hip_runtime.h>
#include <hip/hip_bf16.h>

// EnhancedSpatioTemporalLayer forward, round 8.
// AB (per (b,t)): conv -> small GEMM -> Z[b][o][t][m] bf16 (m contiguous).
// C  (per (b, o-PAIR, t32)): stage 2 Z slices to LDS, each cheb fragment
//    feeds 12 MFMAs (2 o x 2 ti x 3 nt per wave), full-line t-major stores.

#define Bx   16
#define FINx 3
#define Nx   170
#define Tx   288
#define Hx   64
#define Ox   64
#define Kx   3
#define NP   192            // padded n/m (12 x 16)
#define TMW  72             // sTm row stride (bf16): 144B -> 2-way banks
#define NBT  (Bx * Tx)      // 4608
#define ZMW  584            // C: LDS Z row stride in bf16 (1168B)

#define CHEBF_ELEMS (Kx * 6 * 12 * 64 * 8)   // 110592: [sg=k*6+s][nt][lane][8]
#define THF_ELEMS   (Kx * 2 * 4 * 64 * 8)    // 12288:  [k][s][ot][lane][8]
#define ZELEMS ((size_t)Bx * Ox * Tx * 576)  // 169,869,312 (~340 MB bf16)
#define ZBYTES (ZELEMS * 2)

typedef __attribute__((ext_vector_type(8))) short bf16x8;
typedef __attribute__((ext_vector_type(4))) short bf16x4;
typedef __attribute__((ext_vector_type(4))) float f32x4;

__device__ __align__(16) __hip_bfloat16 g_chebfrag[CHEBF_ELEMS];
__device__ __align__(16) __hip_bfloat16 g_thfrag[THF_ELEMS];
__device__ __align__(16) __hip_bfloat16 g_Z[ZELEMS];   // fallback Z buffer

static __device__ __forceinline__ short f2bf(float f) {
    __hip_bfloat16 h = __float2bfloat16(f);
    return *reinterpret_cast<short*>(&h);
}

// g_chebfrag[((sg*12+nt)*64+lane)*8+j] = cheb_k[n][m], sg = k*6+s,
//     n = nt*16 + (lane&15), m = s*32 + (lane>>4)*8 + j   (0 outside 170)
// g_thfrag [(((k*2+s)*4+ot)*64+lane)*8+j] = theta[k][c][o],
//     o = ot*16 + (lane&15), c = s*32 + (lane>>4)*8 + j
__global__ __launch_bounds__(512)
void precompute_frag(const float* __restrict__ cheb, const float* __restrict__ theta) {
    int idx = blockIdx.x * 512 + threadIdx.x;
    if (idx < CHEBF_ELEMS) {
        int j = idx & 7, lane = (idx >> 3) & 63, rest = idx >> 9;
        int nt = rest % 12; rest /= 12;
        int s = rest % 6, k = rest / 6;
        int n = nt * 16 + (lane & 15);
        int m = s * 32 + (lane >> 4) * 8 + j;
        float v = (n < Nx && m < Nx) ? cheb[(k * Nx + n) * Nx + m] : 0.f;
        g_chebfrag[idx] = __float2bfloat16(v);
    } else if (idx < CHEBF_ELEMS + THF_ELEMS) {
        int jdx = idx - CHEBF_ELEMS;
        int j = jdx & 7, lane = (jdx >> 3) & 63, rest = jdx >> 9;
        int ot = rest % 4; rest /= 4;
        int s = rest % 2, k = rest / 2;
        int o = ot * 16 + (lane & 15);
        int c = s * 32 + (lane >> 4) * 8 + j;
        g_thfrag[jdx] = __float2bfloat16(theta[(k * Hx + c) * Ox + o]);
    }
}

// ---------------- AB: conv + theta GEMM -> Z[b][o][t][m] ----------------
__global__ __launch_bounds__(256, 4)
void stgcn_ab(const float* __restrict__ x,
              const float* __restrict__ conv_w,
              const float* __restrict__ conv_b,
              __hip_bfloat16* __restrict__ Z) {
    __shared__ __align__(16) __hip_bfloat16 sTm[NP * TMW];  // 27.6 KB
    __shared__ float sXs[Nx * 9];                           // 6.1 KB

    const int tid = threadIdx.x;
    const int vid = (blockIdx.x & 7) * 576 + (blockIdx.x >> 3);
    const int b  = vid / Tx;
    const int t0 = vid % Tx;

    for (int idx = tid; idx < Nx * 9; idx += 256) {
        int n = idx / 9, r = idx % 9, f = r / 3, j = r % 3;
        int tt = t0 - 1 + j;
        float v = 0.f;
        if (tt >= 0 && tt < Tx) v = x[((b * FINx + f) * Nx + n) * Tx + tt];
        sXs[idx] = v;
    }
    const int cc = tid & 63;
    float wreg[9];
#pragma unroll
    for (int r = 0; r < 9; ++r) wreg[r] = conv_w[cc * 9 + r];
    const float bias = conv_b[cc];
    __syncthreads();

    for (int m = (tid >> 6); m < Nx; m += 4) {
        float acc = bias;
#pragma unroll
        for (int r = 0; r < 9; ++r) acc += sXs[m * 9 + r] * wreg[r];
        sTm[m * TMW + cc] = __float2bfloat16(fmaxf(acc, 0.f));
    }
    for (int idx = tid; idx < (NP - Nx) * 64; idx += 256) {
        int m = Nx + idx / 64, c = idx % 64;
        sTm[m * TMW + c] = __float2bfloat16(0.f);
    }
    __syncthreads();

    const int lane = tid & 63;
    const int w    = tid >> 6;     // 0..3: m-tiles w*3..w*3+2
    const int l16  = lane & 15;
    const int lk   = lane >> 4;
    __hip_bfloat16* zb = Z + ((size_t)(b * Ox) * Tx + t0) * 576;

    for (int k = 0; k < Kx; ++k) {
        f32x4 accs[3][4];
#pragma unroll
        for (int j = 0; j < 3; ++j)
#pragma unroll
            for (int u = 0; u < 4; ++u) accs[j][u] = (f32x4)0.f;

#pragma unroll
        for (int s = 0; s < 2; ++s) {
            bf16x8 afr[3], bfr[4];
#pragma unroll
            for (int j = 0; j < 3; ++j)
                afr[j] = *(const bf16x8*)((const char*)sTm +
                         ((w * 3 + j) * 16 + l16) * (TMW * 2) + s * 64 + lk * 16);
#pragma unroll
            for (int u = 0; u < 4; ++u)
                bfr[u] = *(const bf16x8*)(&g_thfrag[(((k * 2 + s) * 4 + u) * 64 + lane) * 8]);
            // mfma(Tm, theta): D col(l16) = o, row(lk*4+r) = m (4 consecutive)
#pragma unroll
            for (int j = 0; j < 3; ++j)
#pragma unroll
                for (int u = 0; u < 4; ++u)
                    accs[j][u] = __builtin_amdgcn_mfma_f32_16x16x32_bf16(afr[j], bfr[u], accs[j][u], 0, 0, 0);
        }
#pragma unroll
        for (int j = 0; j < 3; ++j)
#pragma unroll
            for (int u = 0; u < 4; ++u) {
                int o  = u * 16 + l16;
                int mm = k * NP + (w * 3 + j) * 16 + lk * 4;
                bf16x4 v;
#pragma unroll
                for (int r = 0; r < 4; ++r) v[r] = f2bf(accs[j][u][r]);
                *(bf16x4*)(zb + (size_t)o * (Tx * 576) + mm) = v;
            }
    }
}

// ---------------- C: o-pair Z->LDS staged big GEMM + epilogue ----------------
// block: (b, o-pair, t32). 256 thr (4 waves). wave w owns n-tiles w*3..w*3+2,
// and computes BOTH o slices x both 16-t halves from each cheb fragment.
__global__ __launch_bounds__(256, 2)
void stgcn_c3(const __hip_bfloat16* __restrict__ Z,
              const float* __restrict__ x,
              const float* __restrict__ res_w,
              const float* __restrict__ res_b,
              float* __restrict__ out) {
    __shared__ __align__(16) __hip_bfloat16 sZ[2][32 * ZMW];   // 74.8 KB

    const int tid = threadIdx.x;
    const int vid = (blockIdx.x & 7) * 576 + (blockIdx.x >> 3);  // 4608 = 8*576
    const int b   = vid / 288;
    const int rem = vid % 288;
    const int tt  = rem / 32;      // t-tile of 32 (0..8)
    const int op  = rem % 32;      // o-pair
    const int o0  = op * 2;
    const int tbase = tt * 32;

    // ---- stage 2 Z slices [32 t][576 m] -> LDS rows padded to ZMW ----
#pragma unroll
    for (int oi = 0; oi < 2; ++oi) {
        const __hip_bfloat16* zsrc = Z + ((size_t)(b * Ox + o0 + oi) * Tx + tbase) * 576;
#pragma unroll
        for (int it = 0; it < 9; ++it) {
            int chunk = it * 256 + tid;        // 16B chunks: 32 rows x 72
            int row = chunk / 72, cs = chunk % 72;
            int4 v = *(const int4*)(zsrc + (size_t)row * 576 + cs * 8);
            *(int4*)(&sZ[oi][row * ZMW + cs * 8]) = v;
        }
    }
    __syncthreads();

    const int lane = tid & 63;
    const int w    = tid >> 6;     // n-tiles w*3+ni
    const int l16  = lane & 15;
    const int lk   = lane >> 4;

    f32x4 acc[3][2][2];            // [ni][oi][ti]
#pragma unroll
    for (int ni = 0; ni < 3; ++ni)
#pragma unroll
        for (int oi = 0; oi < 2; ++oi)
#pragma unroll
            for (int ti = 0; ti < 2; ++ti) acc[ni][oi][ti] = (f32x4)0.f;

#pragma unroll
    for (int s = 0; s < 18; ++s) {
        bf16x8 cf[3], zf[2][2];
#pragma unroll
        for (int ni = 0; ni < 3; ++ni)
            cf[ni] = *(const bf16x8*)(&g_chebfrag[((s * 12 + w * 3 + ni) * 64 + lane) * 8]);
#pragma unroll
        for (int oi = 0; oi < 2; ++oi)
#pragma unroll
            for (int ti = 0; ti < 2; ++ti)
                zf[oi][ti] = *(const bf16x8*)(&sZ[oi][(ti * 16 + l16) * ZMW + s * 32 + lk * 8]);
        // mfma(cheb, Z): D col(l16) = t, row(lk*4+r) = n
#pragma unroll
        for (int ni = 0; ni < 3; ++ni)
#pragma unroll
            for (int oi = 0; oi < 2; ++oi)
#pragma unroll
                for (int ti = 0; ti < 2; ++ti)
                    acc[ni][oi][ti] = __builtin_amdgcn_mfma_f32_16x16x32_bf16(cf[ni], zf[oi][ti], acc[ni][oi][ti], 0, 0, 0);
    }

    // ---- epilogue: relu + residual, t-major full-line stores (x2 o) ----
    const float rw[2][3] = {
        { res_w[o0 * 3 + 0], res_w[o0 * 3 + 1], res_w[o0 * 3 + 2] },
        { res_w[o0 * 3 + 3], res_w[o0 * 3 + 4], res_w[o0 * 3 + 5] } };
    const float rb[2] = { res_b[o0], res_b[o0 + 1] };
    const float* xb = x + (size_t)(b * FINx) * Nx * Tx;

#pragma unroll
    for (int ni = 0; ni < 3; ++ni) {
#pragma unroll
        for (int r = 0; r < 4; ++r) {
            const int n = (w * 3 + ni) * 16 + lk * 4 + r;
            if (n < Nx) {
#pragma unroll
                for (int ti = 0; ti < 2; ++ti) {
                    const int t = tbase + ti * 16 + l16;
                    float xf0 = xb[(0 * Nx + n) * Tx + t];
                    float xf1 = xb[(1 * Nx + n) * Tx + t];
                    float xf2 = xb[(2 * Nx + n) * Tx + t];
#pragma unroll
                    for (int oi = 0; oi < 2; ++oi) {
                        float resv = rb[oi] + xf0 * rw[oi][0] + xf1 * rw[oi][1]
                                            + xf2 * rw[oi][2];
                        out[((size_t)(b * Ox + o0 + oi) * Nx + n) * Tx + t] =
                            fmaxf(acc[ni][oi][ti][r], 0.f) + resv;
                    }
                }
            }
        }
    }
}

extern "C" void kernel_launch(void* const* d_in, const int* in_sizes, int n_in,
                              void* d_out, int out_size, void* d_ws, size_t ws_size,
                              hipStream_t stream) {
    const float* x      = (const float*)d_in[0];
    const float* cheb   = (const float*)d_in[2];
    const float* conv_w = (const float*)d_in[3];
    const float* conv_b = (const float*)d_in[4];
    const float* theta  = (const float*)d_in[5];
    const float* res_w  = (const float*)d_in[6];
    const float* res_b  = (const float*)d_in[7];
    float* out = (float*)d_out;

    __hip_bfloat16* zptr;
    if (ws_size >= ZBYTES) {
        zptr = (__hip_bfloat16*)d_ws;
    } else {
        void* sym = nullptr;
        hipGetSymbolAddress(&sym, HIP_SYMBOL(g_Z));
        zptr = (__hip_bfloat16*)sym;
    }

    int pre_elems = CHEBF_ELEMS + THF_ELEMS;
    hipLaunchKernelGGL(precompute_frag, dim3((pre_elems + 511) / 512), dim3(512), 0, stream,
                       cheb, theta);
    hipLaunchKernelGGL(stgcn_ab, dim3(NBT), dim3(256), 0, stream,
                       x, conv_w, conv_b, zptr);
    hipLaunchKernelGGL(stgcn_c3, dim3(NBT), dim3(256), 0, stream,
                       zptr, x, res_w, res_b, out);
}

// Round 9
// 371.084 us; speedup vs baseline: 1.0506x; 1.0506x over previous
//
#include <hip/hip_runtime.h>
#include <hip/hip_bf16.h>

// EnhancedSpatioTemporalLayer forward, round 9.
// AB (per (b,t)): conv -> small GEMM -> Z[b][o][t][m] bf16 (m contiguous).
// C  (per (b, o, t32)): Z slice staged via global_load_lds (width 16) into
//    LINEAR LDS with pre-swizzled global source (XOR involution); zf reads
//    apply the same XOR. Full-line t-major stores. 4 blocks/CU.

#define Bx   16
#define FINx 3
#define Nx   170
#define Tx   288
#define Hx   64
#define Ox   64
#define Kx   3
#define NP   192            // padded n/m (12 x 16)
#define TMW  72             // sTm row stride (bf16): 144B -> 2-way banks
#define NBT  (Bx * Tx)      // 4608
#define ZROW 1152           // C: LDS Z row stride bytes (576 bf16, LINEAR for gload_lds)

#define CHEBF_ELEMS (Kx * 6 * 12 * 64 * 8)   // 110592: [sg=k*6+s][nt][lane][8]
#define THF_ELEMS   (Kx * 2 * 4 * 64 * 8)    // 12288:  [k][s][ot][lane][8]
#define ZELEMS ((size_t)Bx * Ox * Tx * 576)  // 169,869,312 (~340 MB bf16)
#define ZBYTES (ZELEMS * 2)

typedef __attribute__((ext_vector_type(8))) short bf16x8;
typedef __attribute__((ext_vector_type(4))) short bf16x4;
typedef __attribute__((ext_vector_type(4))) float f32x4;

__device__ __align__(16) __hip_bfloat16 g_chebfrag[CHEBF_ELEMS];
__device__ __align__(16) __hip_bfloat16 g_thfrag[THF_ELEMS];
__device__ __align__(16) __hip_bfloat16 g_Z[ZELEMS];   // fallback Z buffer

static __device__ __forceinline__ short f2bf(float f) {
    __hip_bfloat16 h = __float2bfloat16(f);
    return *reinterpret_cast<short*>(&h);
}

// g_chebfrag[((sg*12+nt)*64+lane)*8+j] = cheb_k[n][m], sg = k*6+s,
//     n = nt*16 + (lane&15), m = s*32 + (lane>>4)*8 + j   (0 outside 170)
// g_thfrag [(((k*2+s)*4+ot)*64+lane)*8+j] = theta[k][c][o],
//     o = ot*16 + (lane&15), c = s*32 + (lane>>4)*8 + j
__global__ __launch_bounds__(512)
void precompute_frag(const float* __restrict__ cheb, const float* __restrict__ theta) {
    int idx = blockIdx.x * 512 + threadIdx.x;
    if (idx < CHEBF_ELEMS) {
        int j = idx & 7, lane = (idx >> 3) & 63, rest = idx >> 9;
        int nt = rest % 12; rest /= 12;
        int s = rest % 6, k = rest / 6;
        int n = nt * 16 + (lane & 15);
        int m = s * 32 + (lane >> 4) * 8 + j;
        float v = (n < Nx && m < Nx) ? cheb[(k * Nx + n) * Nx + m] : 0.f;
        g_chebfrag[idx] = __float2bfloat16(v);
    } else if (idx < CHEBF_ELEMS + THF_ELEMS) {
        int jdx = idx - CHEBF_ELEMS;
        int j = jdx & 7, lane = (jdx >> 3) & 63, rest = jdx >> 9;
        int ot = rest % 4; rest /= 4;
        int s = rest % 2, k = rest / 2;
        int o = ot * 16 + (lane & 15);
        int c = s * 32 + (lane >> 4) * 8 + j;
        g_thfrag[jdx] = __float2bfloat16(theta[(k * Hx + c) * Ox + o]);
    }
}

// ---------------- AB: conv + theta GEMM -> Z[b][o][t][m] ----------------
__global__ __launch_bounds__(256, 4)
void stgcn_ab(const float* __restrict__ x,
              const float* __restrict__ conv_w,
              const float* __restrict__ conv_b,
              __hip_bfloat16* __restrict__ Z) {
    __shared__ __align__(16) __hip_bfloat16 sTm[NP * TMW];  // 27.6 KB
    __shared__ float sXs[Nx * 9];                           // 6.1 KB

    const int tid = threadIdx.x;
    const int vid = (blockIdx.x & 7) * 576 + (blockIdx.x >> 3);
    const int b  = vid / Tx;
    const int t0 = vid % Tx;

    for (int idx = tid; idx < Nx * 9; idx += 256) {
        int n = idx / 9, r = idx % 9, f = r / 3, j = r % 3;
        int tt = t0 - 1 + j;
        float v = 0.f;
        if (tt >= 0 && tt < Tx) v = x[((b * FINx + f) * Nx + n) * Tx + tt];
        sXs[idx] = v;
    }
    const int cc = tid & 63;
    float wreg[9];
#pragma unroll
    for (int r = 0; r < 9; ++r) wreg[r] = conv_w[cc * 9 + r];
    const float bias = conv_b[cc];
    __syncthreads();

    for (int m = (tid >> 6); m < Nx; m += 4) {
        float acc = bias;
#pragma unroll
        for (int r = 0; r < 9; ++r) acc += sXs[m * 9 + r] * wreg[r];
        sTm[m * TMW + cc] = __float2bfloat16(fmaxf(acc, 0.f));
    }
    for (int idx = tid; idx < (NP - Nx) * 64; idx += 256) {
        int m = Nx + idx / 64, c = idx % 64;
        sTm[m * TMW + c] = __float2bfloat16(0.f);
    }
    __syncthreads();

    const int lane = tid & 63;
    const int w    = tid >> 6;     // 0..3: m-tiles w*3..w*3+2
    const int l16  = lane & 15;
    const int lk   = lane >> 4;
    __hip_bfloat16* zb = Z + ((size_t)(b * Ox) * Tx + t0) * 576;

    for (int k = 0; k < Kx; ++k) {
        f32x4 accs[3][4];
#pragma unroll
        for (int j = 0; j < 3; ++j)
#pragma unroll
            for (int u = 0; u < 4; ++u) accs[j][u] = (f32x4)0.f;

#pragma unroll
        for (int s = 0; s < 2; ++s) {
            bf16x8 afr[3], bfr[4];
#pragma unroll
            for (int j = 0; j < 3; ++j)
                afr[j] = *(const bf16x8*)((const char*)sTm +
                         ((w * 3 + j) * 16 + l16) * (TMW * 2) + s * 64 + lk * 16);
#pragma unroll
            for (int u = 0; u < 4; ++u)
                bfr[u] = *(const bf16x8*)(&g_thfrag[(((k * 2 + s) * 4 + u) * 64 + lane) * 8]);
            // mfma(Tm, theta): D col(l16) = o, row(lk*4+r) = m (4 consecutive)
#pragma unroll
            for (int j = 0; j < 3; ++j)
#pragma unroll
                for (int u = 0; u < 4; ++u)
                    accs[j][u] = __builtin_amdgcn_mfma_f32_16x16x32_bf16(afr[j], bfr[u], accs[j][u], 0, 0, 0);
        }
#pragma unroll
        for (int j = 0; j < 3; ++j)
#pragma unroll
            for (int u = 0; u < 4; ++u) {
                int o  = u * 16 + l16;
                int mm = k * NP + (w * 3 + j) * 16 + lk * 4;
                bf16x4 v;
#pragma unroll
                for (int r = 0; r < 4; ++r) v[r] = f2bf(accs[j][u][r]);
                *(bf16x4*)(zb + (size_t)o * (Tx * 576) + mm) = v;
            }
    }
}

// ---------------- C: gload_lds-staged big GEMM + epilogue ----------------
// block: (b, o, t32). 256 thr (4 waves). wave w owns n-tiles w*3..w*3+2.
// LDS Z slice is LINEAR [32t][1152B]; global source pre-XOR-swizzled so
// zf ds_read_b128 with the same XOR is 2-way-bank (free).
__global__ __launch_bounds__(256, 4)
void stgcn_c4(const __hip_bfloat16* __restrict__ Z,
              const float* __restrict__ x,
              const float* __restrict__ res_w,
              const float* __restrict__ res_b,
              float* __restrict__ out) {
    __shared__ __align__(16) char sZb[32 * ZROW];   // 36,864 B, linear

    const int tid = threadIdx.x;
    const int vid = (blockIdx.x & 7) * 1152 + (blockIdx.x >> 3);  // 9216 = 8*1152
    const int b   = vid / 576;
    const int rem = vid % 576;
    const int tt  = rem / 64;      // t-tile of 32 (0..8)
    const int o   = rem % 64;
    const int tbase = tt * 32;

    const int lane = tid & 63;
    const int w    = tid >> 6;

    // ---- stage Z slice [32 t][576 m] via global_load_lds, swizzled source ----
    {
        const char* zsrc = (const char*)(Z + ((size_t)(b * Ox + o) * Tx + tbase) * 576);
#pragma unroll
        for (int i = 0; i < 9; ++i) {
            int chunk = (w * 9 + i) * 1024;          // wave-uniform
            int off   = chunk + lane * 16;           // linear LDS offset this lane fills
            int row   = off / ZROW;
            int soff  = off ^ ((row & 7) << 4);      // involution, stays in-row & in-line
            __builtin_amdgcn_global_load_lds(zsrc + soff, sZb + chunk, 16, 0, 0);
        }
    }
    __syncthreads();

    const int l16  = lane & 15;
    const int lk   = lane >> 4;
    const int zxor = (l16 & 7) << 4;    // row = ti*16+l16 -> row&7 == l16&7

    f32x4 acc[3][2];               // [ni][ti]
#pragma unroll
    for (int ni = 0; ni < 3; ++ni)
#pragma unroll
        for (int ti = 0; ti < 2; ++ti) acc[ni][ti] = (f32x4)0.f;

#pragma unroll
    for (int s = 0; s < 18; ++s) {
        bf16x8 cf[3], zf[2];
#pragma unroll
        for (int ni = 0; ni < 3; ++ni)
            cf[ni] = *(const bf16x8*)(&g_chebfrag[((s * 12 + w * 3 + ni) * 64 + lane) * 8]);
#pragma unroll
        for (int ti = 0; ti < 2; ++ti) {
            int ybyte = (ti * 16 + l16) * ZROW + s * 64 + lk * 16;
            zf[ti] = *(const bf16x8*)(sZb + (ybyte ^ zxor));
        }
        // mfma(cheb, Z): D col(l16) = t, row(lk*4+r) = n
#pragma unroll
        for (int ni = 0; ni < 3; ++ni)
#pragma unroll
            for (int ti = 0; ti < 2; ++ti)
                acc[ni][ti] = __builtin_amdgcn_mfma_f32_16x16x32_bf16(cf[ni], zf[ti], acc[ni][ti], 0, 0, 0);
    }

    // ---- epilogue: relu + residual, t-major full-line stores ----
    const float rw0 = res_w[o * 3 + 0], rw1 = res_w[o * 3 + 1], rw2 = res_w[o * 3 + 2];
    const float rb  = res_b[o];
    float* ob = out + ((size_t)(b * Ox + o) * Nx) * Tx;
    const float* xb = x + (size_t)(b * FINx) * Nx * Tx;

#pragma unroll
    for (int ni = 0; ni < 3; ++ni) {
#pragma unroll
        for (int r = 0; r < 4; ++r) {
            const int n = (w * 3 + ni) * 16 + lk * 4 + r;
            if (n < Nx) {
#pragma unroll
                for (int ti = 0; ti < 2; ++ti) {
                    const int t = tbase + ti * 16 + l16;
                    float xf0 = xb[(0 * Nx + n) * Tx + t];
                    float xf1 = xb[(1 * Nx + n) * Tx + t];
                    float xf2 = xb[(2 * Nx + n) * Tx + t];
                    float resv = rb + xf0 * rw0 + xf1 * rw1 + xf2 * rw2;
                    ob[n * Tx + t] = fmaxf(acc[ni][ti][r], 0.f) + resv;
                }
            }
        }
    }
}

extern "C" void kernel_launch(void* const* d_in, const int* in_sizes, int n_in,
                              void* d_out, int out_size, void* d_ws, size_t ws_size,
                              hipStream_t stream) {
    const float* x      = (const float*)d_in[0];
    const float* cheb   = (const float*)d_in[2];
    const float* conv_w = (const float*)d_in[3];
    const float* conv_b = (const float*)d_in[4];
    const float* theta  = (const float*)d_in[5];
    const float* res_w  = (const float*)d_in[6];
    const float* res_b  = (const float*)d_in[7];
    float* out = (float*)d_out;

    __hip_bfloat16* zptr;
    if (ws_size >= ZBYTES) {
        zptr = (__hip_bfloat16*)d_ws;
    } else {
        void* sym = nullptr;
        hipGetSymbolAddress(&sym, HIP_SYMBOL(g_Z));
        zptr = (__hip_bfloat16*)sym;
    }

    int pre_elems = CHEBF_ELEMS + THF_ELEMS;
    hipLaunchKernelGGL(precompute_frag, dim3((pre_elems + 511) / 512), dim3(512), 0, stream,
                       cheb, theta);
    hipLaunchKernelGGL(stgcn_ab, dim3(NBT), dim3(256), 0, stream,
                       x, conv_w, conv_b, zptr);
    hipLaunchKernelGGL(stgcn_c4, dim3(9216), dim3(256), 0, stream,
                       zptr, x, res_w, res_b, out);
}